// Round 7
// baseline (1155.194 us; speedup 1.0000x reference)
//
#include <hip/hip_runtime.h>
#include <hip/hip_bf16.h>

#define N_NODES 20000
#define N_EDGES 100000
#define HID 512
#define G3 1536   // 3*HID
#define NH 8
#define OD 64

typedef __hip_bfloat16 bf16;
typedef __attribute__((ext_vector_type(8))) short bf16x8;   // 8 bf16 = 4 VGPRs
typedef __attribute__((ext_vector_type(4))) float f32x4;

__device__ __forceinline__ float frcp(float x) { return __builtin_amdgcn_rcpf(x); }
__device__ __forceinline__ float fsig(float x) { return frcp(1.0f + __expf(-x)); }
// saturation-safe fast tanh (rcp-based)
__device__ __forceinline__ float ftanh(float x) { return 1.0f - 2.0f * frcp(__expf(2.0f * x) + 1.0f); }
__device__ __forceinline__ float b2f(bf16 b) { return __bfloat162float(b); }
__device__ __forceinline__ bf16 f2b(float f) { return __float2bfloat16(f); }
__device__ __forceinline__ float bs2f(short s) {
    return __uint_as_float(((unsigned)(unsigned short)s) << 16);
}
__device__ __forceinline__ float us2f(unsigned short s) {
    return __uint_as_float(((unsigned)s) << 16);
}
__device__ __forceinline__ short f2bs(float f) {
    bf16 b = __float2bfloat16(f);
    return *reinterpret_cast<short*>(&b);
}
__device__ __forceinline__ unsigned ford(float f) {
    unsigned u = __float_as_uint(f);
    return (u & 0x80000000u) ? ~u : (u | 0x80000000u);
}
__device__ __forceinline__ float iford(unsigned u) {
    return __uint_as_float((u & 0x80000000u) ? (u & 0x7fffffffu) : ~u);
}

// async global->LDS 16B; falls back to manual copy if builtin missing
__device__ __forceinline__ void g2l16(const void* g, void* l) {
#if __has_builtin(__builtin_amdgcn_global_load_lds)
    __builtin_amdgcn_global_load_lds((const __attribute__((address_space(1))) char*)g,
                                     (__attribute__((address_space(3))) char*)l, 16, 0, 0);
#else
    *(bf16x8*)l = *(const bf16x8*)g;
#endif
}

// G / GH2 layout: gate-interleaved  X[n*1536 + k*3 + g]; H1/h2: row-major [n][512]

// ---- K0: prep weights.
// WTs : 16x16x32 B-frags of W_hh, [g][jt][8192 shorts]
// WIE : 16x16x32 B-frags of W_ih (K-extension chunks 16-17), [g][jt][2][512 shorts]
// featB: bf16 copy of features [20000][64]
__global__ __launch_bounds__(256) void k_prep(const float* __restrict__ Whh,
                                              const float* __restrict__ Wih,
                                              const float* __restrict__ feat,
                                              bf16* __restrict__ WTs,
                                              bf16* __restrict__ WIE,
                                              bf16* __restrict__ featB,
                                              float* __restrict__ WIT) {
    int t = blockIdx.x * 256 + threadIdx.x;   // 1441 blocks -> 368896 exactly
    if (t < 98304) {
        int T = t >> 10, c = (t >> 6) & 15, l = t & 63;
        int n = T * 16 + (l & 15);
        int k = c * 32 + ((l >> 4) << 3);
        const float* src = Whh + (size_t)n * 512 + k;
        bf16x8 v;
#pragma unroll
        for (int j = 0; j < 8; ++j) v[j] = f2bs(src[j]);
        *(bf16x8*)(WTs + (size_t)t * 8) = v;
    } else if (t < 196608) {
        int u = t - 98304;          // WIT[d][j] = Wih[j][d]
        int d = u / 1536, j = u % 1536;
        WIT[u] = Wih[(size_t)j * 64 + d];
    } else if (t < 208896) {
        int u = t - 196608;         // WIE frags: l, cc, jt, g
        int l = u & 63, cc = (u >> 6) & 1, jg = u >> 7;
        int jt = jg & 31, g = jg >> 5;
        int row = g * 512 + jt * 16 + (l & 15);
        int d0 = cc * 32 + ((l >> 4) << 3);
        const float* src = Wih + (size_t)row * 64 + d0;
        bf16x8 v;
#pragma unroll
        for (int j = 0; j < 8; ++j) v[j] = f2bs(src[j]);
        *(bf16x8*)(WIE + (size_t)u * 8) = v;
    } else {
        int u = t - 208896;         // featB: 160000 threads x 8 elems
        const float* src = feat + (size_t)u * 8;
        bf16x8 v;
#pragma unroll
        for (int j = 0; j < 8; ++j) v[j] = f2bs(src[j]);
        *(bf16x8*)(featB + (size_t)u * 8) = v;
    }
}

// ---- CSR build: count / scan / fill
__global__ __launch_bounds__(256) void k_count(const int* __restrict__ dst,
                                               unsigned* __restrict__ cnt) {
    int e = blockIdx.x * 256 + threadIdx.x;
    if (e < N_EDGES) atomicAdd(&cnt[dst[e]], 1u);
}

#define SCAN_CH 79
__global__ __launch_bounds__(256) void k_scan(const unsigned* __restrict__ cnt,
                                              unsigned* __restrict__ base,
                                              unsigned* __restrict__ cursor) {
    __shared__ unsigned ls[256];
    int t = threadIdx.x;
    int s0 = t * SCAN_CH;
    int s1 = s0 + SCAN_CH < N_NODES ? s0 + SCAN_CH : N_NODES;
    unsigned s = 0;
    for (int i = s0; i < s1; ++i) s += cnt[i];
    ls[t] = s;
    __syncthreads();
    for (int d = 1; d < 256; d <<= 1) {
        unsigned v = (t >= d) ? ls[t - d] : 0u;
        __syncthreads();
        ls[t] += v;
        __syncthreads();
    }
    unsigned run = ls[t] - s;
    for (int i = s0; i < s1; ++i) {
        base[i] = run; cursor[i] = run; run += cnt[i];
    }
    if (t == 255) base[N_NODES] = ls[255];
}

__global__ __launch_bounds__(256) void k_fill(const int* __restrict__ dst,
                                              unsigned* __restrict__ cursor,
                                              unsigned* __restrict__ csr) {
    int e = blockIdx.x * 256 + threadIdx.x;
    if (e < N_EDGES) {
        unsigned p = atomicAdd(&cursor[dst[e]], 1u);
        csr[p] = (unsigned)e;
    }
}

// ---- K1: G[n][k][g] = features[n].W_ih + b_ih (interleaved); also H1[n][k] (free)
__global__ __launch_bounds__(256) void k_gi(const float* __restrict__ feat,
                                            const float* __restrict__ WIT,
                                            const float* __restrict__ b_ih,
                                            const float* __restrict__ b_hh,
                                            bf16* __restrict__ G,
                                            bf16* __restrict__ H1) {
    __shared__ float fs[16][64];
    const int n0 = blockIdx.x * 16;
    const int k = blockIdx.y * 256 + threadIdx.x;
    for (int i = threadIdx.x; i < 16 * 64; i += 256)
        fs[0][i] = feat[(size_t)n0 * 64 + i];
    __syncthreads();
    float acc[3][16];
#pragma unroll
    for (int g = 0; g < 3; ++g) {
        float b = b_ih[g * 512 + k];
#pragma unroll
        for (int e = 0; e < 16; ++e) acc[g][e] = b;
    }
    for (int d = 0; d < 64; d += 4) {
        float w[3][4];
#pragma unroll
        for (int u = 0; u < 4; ++u)
#pragma unroll
            for (int g = 0; g < 3; ++g)
                w[g][u] = WIT[(size_t)(d + u) * G3 + g * 512 + k];
#pragma unroll
        for (int e = 0; e < 16; ++e) {
            float4 f = *(const float4*)&fs[e][d];
#pragma unroll
            for (int g = 0; g < 3; ++g)
                acc[g][e] += w[g][0] * f.x + w[g][1] * f.y + w[g][2] * f.z + w[g][3] * f.w;
        }
    }
    const float br = b_hh[k], bz = b_hh[512 + k], bn = b_hh[1024 + k];
#pragma unroll
    for (int e = 0; e < 16; ++e) {
        bf16* dst = G + (size_t)(n0 + e) * G3 + k * 3;
        dst[0] = f2b(acc[0][e]);
        dst[1] = f2b(acc[1][e]);
        dst[2] = f2b(acc[2][e]);
        float r1 = fsig(acc[0][e] + br);
        float z1 = fsig(acc[1][e] + bz);
        float n1 = ftanh(acc[2][e] + r1 * bn);
        H1[(size_t)(n0 + e) * HID + k] = f2b((1.0f - z1) * n1);
    }
}

// ---- K2: GH2[n] = H1[n] @ W_hh^T + b_hh. M=128/block, 2 m-tiles per wave,
// per-gate double-buffered staging (2x16 KB LDS), LDS-tile epilogue.
__global__ __launch_bounds__(256, 2) void k_gh2(const bf16* __restrict__ H1,
                                                const bf16* __restrict__ WTs,
                                                const float* __restrict__ b_hh,
                                                bf16* __restrict__ GH2) {
    __shared__ short Bs[2][8192];       // 32 KB
    __shared__ short tile2[128 * 48];   // 12 KB output tile
    const int tid = threadIdx.x;
    const int wave = tid >> 6, lane = tid & 63;
    const int m0 = blockIdx.x * 128;
    const int k0 = (lane >> 4) << 3;

    bf16x8 afrag[2][16];
#pragma unroll
    for (int t = 0; t < 2; ++t) {
        int row = m0 + wave * 32 + t * 16 + (lane & 15);
        int ar = row < N_NODES ? row : N_NODES - 1;
#pragma unroll
        for (int c = 0; c < 16; ++c)
            afrag[t][c] = *(const bf16x8*)(H1 + (size_t)ar * HID + c * 32 + k0);
    }

    const int col = lane & 15;
    const int qb = (lane >> 4) << 2;
    const int boff = lane * 8;

    // prologue: stage (jt=0, gate=0) into buf 0
#pragma unroll
    for (int i = 0; i < 4; ++i) {
        int q = tid + i * 256;
        g2l16(WTs + (size_t)q * 8, &Bs[0][q * 8]);
    }
    __syncthreads();

    int cur = 0;
    for (int jt = 0; jt < 32; ++jt) {
        const int cj = jt * 16 + col;
        f32x4 acc[2][3];
#pragma unroll
        for (int t = 0; t < 2; ++t)
#pragma unroll
            for (int g = 0; g < 3; ++g) acc[t][g] = (f32x4){0, 0, 0, 0};
        const float br = b_hh[cj], bz = b_hh[512 + cj], bn = b_hh[1024 + cj];
        // ---- phase gate 0: store prev-jt tile (coalesced), stage gate1, compute gate0
        {
            if (jt > 0) {
                int pj = jt - 1;
#pragma unroll
                for (int i_ = 0; i_ < 3; ++i_) {
                    int idx = i_ * 256 + tid;     // [0,768): row=idx/6, chunk=idx%6
                    int rg = m0 + (idx / 6);
                    if (rg < N_NODES)
                        *(bf16x8*)(GH2 + (size_t)rg * G3 + pj * 48 + (idx % 6) * 8) =
                            *(const bf16x8*)&tile2[idx * 8];
                }
            }
#pragma unroll
            for (int i = 0; i < 4; ++i) {
                int q = tid + i * 256;
                g2l16(WTs + 262144 + (size_t)jt * 8192 + q * 8, &Bs[cur ^ 1][q * 8]);
            }
            const short* cb = &Bs[cur][0];
#pragma unroll
            for (int c = 0; c < 16; ++c) {
                bf16x8 b = *(const bf16x8*)&cb[c * 512 + boff];
                acc[0][0] = __builtin_amdgcn_mfma_f32_16x16x32_bf16(afrag[0][c], b, acc[0][0], 0, 0, 0);
                acc[1][0] = __builtin_amdgcn_mfma_f32_16x16x32_bf16(afrag[1][c], b, acc[1][0], 0, 0, 0);
            }
            __syncthreads();
            cur ^= 1;
        }
        // ---- phase gate 1: stage gate2, compute gate1
        {
#pragma unroll
            for (int i = 0; i < 4; ++i) {
                int q = tid + i * 256;
                g2l16(WTs + 524288 + (size_t)jt * 8192 + q * 8, &Bs[cur ^ 1][q * 8]);
            }
            const short* cb = &Bs[cur][0];
#pragma unroll
            for (int c = 0; c < 16; ++c) {
                bf16x8 b = *(const bf16x8*)&cb[c * 512 + boff];
                acc[0][1] = __builtin_amdgcn_mfma_f32_16x16x32_bf16(afrag[0][c], b, acc[0][1], 0, 0, 0);
                acc[1][1] = __builtin_amdgcn_mfma_f32_16x16x32_bf16(afrag[1][c], b, acc[1][1], 0, 0, 0);
            }
            __syncthreads();
            cur ^= 1;
        }
        // ---- phase gate 2: stage next jt gate0, compute gate2, epilogue -> LDS tile
        {
            if (jt < 31) {
#pragma unroll
                for (int i = 0; i < 4; ++i) {
                    int q = tid + i * 256;
                    g2l16(WTs + (size_t)(jt + 1) * 8192 + q * 8, &Bs[cur ^ 1][q * 8]);
                }
            }
            const short* cb = &Bs[cur][0];
#pragma unroll
            for (int c = 0; c < 16; ++c) {
                bf16x8 b = *(const bf16x8*)&cb[c * 512 + boff];
                acc[0][2] = __builtin_amdgcn_mfma_f32_16x16x32_bf16(afrag[0][c], b, acc[0][2], 0, 0, 0);
                acc[1][2] = __builtin_amdgcn_mfma_f32_16x16x32_bf16(afrag[1][c], b, acc[1][2], 0, 0, 0);
            }
#pragma unroll
            for (int t = 0; t < 2; ++t)
#pragma unroll
                for (int q = 0; q < 4; ++q) {
                    int lr = wave * 32 + t * 16 + qb + q;
                    short* s = &tile2[lr * 48 + col * 3];
                    s[0] = f2bs(acc[t][0][q] + br);
                    s[1] = f2bs(acc[t][1][q] + bz);
                    s[2] = f2bs(acc[t][2][q] + bn);
                }
            __syncthreads();
            cur ^= 1;
        }
    }
    // flush jt=31 tile (last gate-2 barrier already passed)
#pragma unroll
    for (int i_ = 0; i_ < 3; ++i_) {
        int idx = i_ * 256 + tid;
        int rg = m0 + (idx / 6);
        if (rg < N_NODES)
            *(bf16x8*)(GH2 + (size_t)rg * G3 + 31 * 48 + (idx % 6) * 8) =
                *(const bf16x8*)&tile2[idx * 8];
    }
}

// ---- K3: per-edge h2 = GRUstep2(G[i1], GH2[i0], H1[i0]) elementwise
__global__ __launch_bounds__(256) void k_h2(const bf16* __restrict__ G,
                                            const bf16* __restrict__ GH2,
                                            const bf16* __restrict__ H1,
                                            const int* __restrict__ emi,
                                            bf16* __restrict__ h2) {
    size_t i = (size_t)blockIdx.x * 256 + threadIdx.x;   // 25000 blocks exactly
    int e = (int)(i >> 6);
    int kc = (int)(i & 63) * 8;
    int i0 = emi[(size_t)e * 3 + 0];
    int i1 = emi[(size_t)e * 3 + 1];
    const bf16* g1p = G + (size_t)i1 * G3 + kc * 3;
    const bf16* ghp = GH2 + (size_t)i0 * G3 + kc * 3;
    bf16x8 h1v = *(const bf16x8*)(H1 + (size_t)i0 * HID + kc);
    short s1[24], sh[24];
    {
        bf16x8 a0 = *(const bf16x8*)g1p, a1 = *(const bf16x8*)(g1p + 8), a2 = *(const bf16x8*)(g1p + 16);
        bf16x8 c0 = *(const bf16x8*)ghp, c1 = *(const bf16x8*)(ghp + 8), c2 = *(const bf16x8*)(ghp + 16);
#pragma unroll
        for (int j = 0; j < 8; ++j) {
            s1[j] = a0[j]; s1[8 + j] = a1[j]; s1[16 + j] = a2[j];
            sh[j] = c0[j]; sh[8 + j] = c1[j]; sh[16 + j] = c2[j];
        }
    }
    bf16x8 out;
#pragma unroll
    for (int j = 0; j < 8; ++j) {
        float r = fsig(bs2f(s1[j * 3 + 0]) + bs2f(sh[j * 3 + 0]));
        float z = fsig(bs2f(s1[j * 3 + 1]) + bs2f(sh[j * 3 + 1]));
        float n = ftanh(bs2f(s1[j * 3 + 2]) + r * bs2f(sh[j * 3 + 2]));
        out[j] = f2bs((1.0f - z) * n + z * bs2f(h1v[j]));
    }
    *(bf16x8*)(h2 + (size_t)e * HID + kc) = out;
}

// ---- K4: BARRIER-FREE h3 = GRUstep3. Output columns partitioned across
// blocks: cg = 16 cols -> W-slice (3x16KB Whh + 3x2KB Wih-ext = 54 KB) lives
// in LDS for the whole kernel (loaded once, ONE barrier). The m-loop streams
// edges with ZERO barriers: A-frags from read-only h2, 108 MFMAs over 8
// independent chains per wave, register-only GRU epilogue to h3out (separate
// buffer — in-place h2 update would race under column-split). XCD-swizzled
// bid so the 32 col-group blocks of one m-tile co-reside per XCD and share
// the A-panel in L2. This removes the 96-phase barrier machine that was
// invariant (291-305us) across R0-R6's six structural variants.
__global__ __launch_bounds__(256, 2) void k_gemm3(const bf16* __restrict__ featB,
                                                  const bf16* __restrict__ WTs,
                                                  const bf16* __restrict__ WIE,
                                                  const float* __restrict__ b_ih,
                                                  const float* __restrict__ b_hh,
                                                  const int* __restrict__ emi,
                                                  const bf16* __restrict__ h2,
                                                  bf16* __restrict__ h3out) {
    __shared__ short Ws[3][8192];   // 48 KB: W_hh cg-slice (16 cols x K=512)
    __shared__ short We[3][1024];   // 6 KB: W_ih ext (16 cols x D=64)
    const int tid = threadIdx.x;
    const int wave = tid >> 6, lane = tid & 63;
    const int bid = blockIdx.x;                 // 768 = 8 XCD x (3 mt x 32 cg)
    const int xcd = bid & 7, sl = bid >> 3;
    const int mt = xcd * 3 + (sl >> 5);
    const int cg = sl & 31;
    const int mbase = mt * 4224;                // 24 mt x 4224 = 101376 (clamped)
    const int col = lane & 15;
    const int cj = cg * 16 + col;
    const int k0 = (lane >> 4) << 3;
    const int qb = (lane >> 4) << 2;
    const int boff = lane * 8;

    // load W slice once
#pragma unroll
    for (int g = 0; g < 3; ++g) {
#pragma unroll
        for (int i = 0; i < 4; ++i) {
            int q = tid + i * 256;
            g2l16(WTs + (size_t)g * 262144 + (size_t)cg * 8192 + q * 8, &Ws[g][q * 8]);
        }
        if (tid < 128)
            g2l16(WIE + (size_t)g * 32768 + (size_t)cg * 1024 + tid * 8, &We[g][tid * 8]);
    }
    // per-lane-constant biases (hoisted out of the loop entirely)
    const float rb = b_ih[cj] + b_hh[cj];
    const float zb = b_ih[512 + cj] + b_hh[512 + cj];
    const float nb = b_ih[1024 + cj];
    const float hb = b_hh[1024 + cj];
    __syncthreads();   // the ONLY barrier

    for (int st = 0; st < 33; ++st) {
        const int rowb = mbase + st * 128 + wave * 32;
        // A frags: 2 m-tiles x (16 h2 chunks + 2 featB chunks)
        bf16x8 af[2][18];
#pragma unroll
        for (int t = 0; t < 2; ++t) {
            int row = rowb + t * 16 + (lane & 15);
            int ar = row < N_EDGES ? row : N_EDGES - 1;
#pragma unroll
            for (int c = 0; c < 16; ++c)
                af[t][c] = *(const bf16x8*)(h2 + (size_t)ar * HID + c * 32 + k0);
            int i2 = emi[(size_t)ar * 3 + 2];
            af[t][16] = *(const bf16x8*)(featB + (size_t)i2 * 64 + k0);
            af[t][17] = *(const bf16x8*)(featB + (size_t)i2 * 64 + 32 + k0);
        }
        // old-h2 value for the z-blend (prefetched before the MFMA cluster)
        unsigned short ph[2][4];
#pragma unroll
        for (int t = 0; t < 2; ++t)
#pragma unroll
            for (int q = 0; q < 4; ++q) {
                int row = rowb + t * 16 + qb + q;
                int ec = row < N_EDGES ? row : N_EDGES - 1;
                ph[t][q] = ((const unsigned short*)h2)[(size_t)ec * HID + cj];
            }
        f32x4 ar_[2], az_[2], ahn[2], ain[2];
#pragma unroll
        for (int t = 0; t < 2; ++t) {
            ar_[t] = (f32x4){0, 0, 0, 0}; az_[t] = (f32x4){0, 0, 0, 0};
            ahn[t] = (f32x4){0, 0, 0, 0}; ain[t] = (f32x4){0, 0, 0, 0};
        }
        // 108 MFMAs, 8 independent chains, each B-read feeds 2 MFMAs
#pragma unroll
        for (int c = 0; c < 16; ++c) {
            bf16x8 br = *(const bf16x8*)&Ws[0][c * 512 + boff];
            bf16x8 bz = *(const bf16x8*)&Ws[1][c * 512 + boff];
            bf16x8 bn = *(const bf16x8*)&Ws[2][c * 512 + boff];
#pragma unroll
            for (int t = 0; t < 2; ++t) {
                ar_[t] = __builtin_amdgcn_mfma_f32_16x16x32_bf16(af[t][c], br, ar_[t], 0, 0, 0);
                az_[t] = __builtin_amdgcn_mfma_f32_16x16x32_bf16(af[t][c], bz, az_[t], 0, 0, 0);
                ahn[t] = __builtin_amdgcn_mfma_f32_16x16x32_bf16(af[t][c], bn, ahn[t], 0, 0, 0);
            }
        }
#pragma unroll
        for (int cc = 0; cc < 2; ++cc) {
            bf16x8 br = *(const bf16x8*)&We[0][cc * 512 + boff];
            bf16x8 bz = *(const bf16x8*)&We[1][cc * 512 + boff];
            bf16x8 bn = *(const bf16x8*)&We[2][cc * 512 + boff];
#pragma unroll
            for (int t = 0; t < 2; ++t) {
                ar_[t] = __builtin_amdgcn_mfma_f32_16x16x32_bf16(af[t][16 + cc], br, ar_[t], 0, 0, 0);
                az_[t] = __builtin_amdgcn_mfma_f32_16x16x32_bf16(af[t][16 + cc], bz, az_[t], 0, 0, 0);
                ain[t] = __builtin_amdgcn_mfma_f32_16x16x32_bf16(af[t][16 + cc], bn, ain[t], 0, 0, 0);
            }
        }
        // fused GRU epilogue (register-only operands)
#pragma unroll
        for (int t = 0; t < 2; ++t)
#pragma unroll
            for (int q = 0; q < 4; ++q) {
                int row = rowb + t * 16 + qb + q;
                if (row < N_EDGES) {
                    float r = fsig(ar_[t][q] + rb);
                    float z = fsig(az_[t][q] + zb);
                    float n = ftanh(ain[t][q] + nb + r * (ahn[t][q] + hb));
                    h3out[(size_t)row * HID + cj] =
                        f2b((1.0f - z) * n + z * us2f(ph[t][q]));
                }
            }
    }
}

// ---- K6: attention logits + leaky relu + segment max
__global__ __launch_bounds__(256) void k_logits(const bf16* __restrict__ eft,
                                                const float* __restrict__ attn,
                                                const int* __restrict__ dst,
                                                float* __restrict__ a,
                                                unsigned* __restrict__ amax) {
    int i = blockIdx.x * 256 + threadIdx.x;  // E*NH exactly
    int e = i >> 3, h = i & 7;
    const __hip_bfloat162* f2 = (const __hip_bfloat162*)(eft + (size_t)e * HID + h * OD);
    const float* at = attn + h * OD;
    float s = 0.f;
#pragma unroll
    for (int d = 0; d < OD / 2; ++d) {
        float2 fv = __bfloat1622float2(f2[d]);
        s += fv.x * at[2 * d] + fv.y * at[2 * d + 1];
    }
    s = (s >= 0.f) ? s : 0.01f * s;
    a[i] = s;
    atomicMax(&amax[(size_t)dst[e] * NH + h], ford(s));
}

// ---- K7: ea = exp(a - amax[dst]); denom += ea
__global__ __launch_bounds__(256) void k_ea(const int* __restrict__ dst,
                                            const unsigned* __restrict__ amax,
                                            float* __restrict__ a,
                                            float* __restrict__ denom) {
    int i = blockIdx.x * 256 + threadIdx.x;
    int e = i >> 3, h = i & 7;
    float m = iford(amax[(size_t)dst[e] * NH + h]);
    float v = __expf(a[i] - m);
    a[i] = v;
    atomicAdd(&denom[(size_t)dst[e] * NH + h], v);
}

// ---- K8: out[n][k] = sum_e eft[e][k]*ea[e][h] / denom[n][h]   (CSR, no atomics)
__global__ __launch_bounds__(256) void k_out(const bf16* __restrict__ eft,
                                             const float* __restrict__ a,
                                             const float* __restrict__ denom,
                                             const unsigned* __restrict__ base,
                                             const unsigned* __restrict__ csr,
                                             float* __restrict__ out) {
    int n = blockIdx.x;
    int k = blockIdx.y * 256 + threadIdx.x;
    int h = k >> 6;
    unsigned b0 = base[n], b1 = base[n + 1];
    float rden = (b1 > b0) ? frcp(denom[(size_t)n * NH + h]) : 0.0f;
    float acc = 0.f;
    for (unsigned i = b0; i < b1; ++i) {
        unsigned e = csr[i];
        float al = a[(size_t)e * NH + h];
        acc += b2f(eft[(size_t)e * HID + k]) * al;
    }
    out[(size_t)n * HID + k] = acc * rden;
}

extern "C" void kernel_launch(void* const* d_in, const int* in_sizes, int n_in,
                              void* d_out, int out_size, void* d_ws, size_t ws_size,
                              hipStream_t stream) {
    (void)in_sizes; (void)n_in; (void)ws_size; (void)out_size;
    const float* feat = (const float*)d_in[0];
    const float* W_ih = (const float*)d_in[1];
    const float* W_hh = (const float*)d_in[2];
    const float* b_ih = (const float*)d_in[3];
    const float* b_hh = (const float*)d_in[4];
    const float* attn = (const float*)d_in[5];
    const int* emi = (const int*)d_in[6];
    const int* dst = (const int*)d_in[7];
    float* out = (float*)d_out;

    // workspace layout (bytes) — total ~252.8 MB (proven-safe)
    char* ws = (char*)d_ws;
    bf16* G = (bf16*)ws;                               // 61,440,000 B (interleaved)
    bf16* GH2 = (bf16*)(ws + 61440000);                // 61,440,000 B (interleaved)
    bf16* h2 = (bf16*)(ws + 122880000);                // 102,400,000 B (row-major)
    bf16* WTs = (bf16*)(ws + 225280000);               // 1,572,864 B
    float* WIT = (float*)(ws + 226852864);             // 393,216 B
    float* a = (float*)(ws + 227246080);               // 3,200,000 B
    unsigned* amax = (unsigned*)(ws + 230446080);      // 640,000 B
    float* denom = (float*)(ws + 231086080);           // 640,000 B
    unsigned* cnt = (unsigned*)(ws + 231726080);       // 80,000 B
    unsigned* base = (unsigned*)(ws + 231806080);      // 80,008 B (20001 u32, pad)
    unsigned* cursor = (unsigned*)(ws + 231886088);    // 80,000 B
    unsigned* csr = (unsigned*)(ws + 231966088);       // 400,000 B
    bf16* H1 = (bf16*)(ws + 232366088);                // 20,480,000 B -> end 252,846,088
    // WIE + featB ALIAS the `a` buffer (written k_prep, read k_gemm3, dead
    // before k_logits writes `a`).
    bf16* WIE = (bf16*)(ws + 227246080);               // 196,608 B
    bf16* featB = (bf16*)(ws + 227442688);             // 2,560,000 B -> 230,002,688
    // h3out (102.4 MB) ALIASES G+GH2 (122.88 MB): G is last read by k_h2,
    // GH2 likewise; k_gemm3 (strictly after on-stream) writes h3out, then
    // k_logits/k_out read it. h2 stays pristine as k_gemm3's A-operand.
    bf16* h3out = (bf16*)ws;

    // zero amax + denom + cnt (contiguous)
    (void)hipMemsetAsync(amax, 0, 1360000, stream);

    k_prep<<<1441, 256, 0, stream>>>(W_hh, W_ih, feat, WTs, WIE, featB, WIT);
    k_count<<<391, 256, 0, stream>>>(dst, cnt);
    k_scan<<<1, 256, 0, stream>>>(cnt, base, cursor);
    k_fill<<<391, 256, 0, stream>>>(dst, cursor, csr);
    k_gi<<<dim3(1250, 2), 256, 0, stream>>>(feat, WIT, b_ih, b_hh, G, H1);
    k_gh2<<<157, 256, 0, stream>>>(H1, WTs, b_hh, GH2);
    k_h2<<<25000, 256, 0, stream>>>(G, GH2, H1, emi, h2);
    k_gemm3<<<768, 256, 0, stream>>>(featB, WTs, WIE, b_ih, b_hh, emi, h2, h3out);
    k_logits<<<3125, 256, 0, stream>>>(h3out, attn, dst, a, amax);
    k_ea<<<3125, 256, 0, stream>>>(dst, amax, a, denom);
    k_out<<<dim3(N_NODES, 2), 256, 0, stream>>>(h3out, a, denom, base, csr, out);
}

// Round 8
// 793.518 us; speedup vs baseline: 1.4558x; 1.4558x over previous
//
#include <hip/hip_runtime.h>
#include <hip/hip_bf16.h>

#define N_NODES 20000
#define N_EDGES 100000
#define HID 512
#define G3 1536   // 3*HID
#define NH 8
#define OD 64

typedef __hip_bfloat16 bf16;
typedef __attribute__((ext_vector_type(8))) short bf16x8;   // 8 bf16 = 4 VGPRs
typedef __attribute__((ext_vector_type(4))) float f32x4;

__device__ __forceinline__ float frcp(float x) { return __builtin_amdgcn_rcpf(x); }
__device__ __forceinline__ float fsig(float x) { return frcp(1.0f + __expf(-x)); }
// saturation-safe fast tanh (rcp-based)
__device__ __forceinline__ float ftanh(float x) { return 1.0f - 2.0f * frcp(__expf(2.0f * x) + 1.0f); }
__device__ __forceinline__ float b2f(bf16 b) { return __bfloat162float(b); }
__device__ __forceinline__ bf16 f2b(float f) { return __float2bfloat16(f); }
__device__ __forceinline__ float bs2f(short s) {
    return __uint_as_float(((unsigned)(unsigned short)s) << 16);
}
__device__ __forceinline__ float us2f(unsigned short s) {
    return __uint_as_float(((unsigned)s) << 16);
}
__device__ __forceinline__ short f2bs(float f) {
    bf16 b = __float2bfloat16(f);
    return *reinterpret_cast<short*>(&b);
}
__device__ __forceinline__ unsigned ford(float f) {
    unsigned u = __float_as_uint(f);
    return (u & 0x80000000u) ? ~u : (u | 0x80000000u);
}
__device__ __forceinline__ float iford(unsigned u) {
    return __uint_as_float((u & 0x80000000u) ? (u & 0x7fffffffu) : ~u);
}

// async global->LDS 16B; falls back to manual copy if builtin missing
__device__ __forceinline__ void g2l16(const void* g, void* l) {
#if __has_builtin(__builtin_amdgcn_global_load_lds)
    __builtin_amdgcn_global_load_lds((const __attribute__((address_space(1))) char*)g,
                                     (__attribute__((address_space(3))) char*)l, 16, 0, 0);
#else
    *(bf16x8*)l = *(const bf16x8*)g;
#endif
}

// G / GH2 layout: gate-interleaved  X[n*1536 + k*3 + g]; H1/h2: row-major [n][512]

// ---- K0: prep weights.
// WTs : 16x16x32 B-frags of W_hh, [g][jt][8192 shorts]
// WIE : 16x16x32 B-frags of W_ih (K-extension chunks 16-17), [g][jt][2][512 shorts]
// featB: bf16 copy of features [20000][64]
__global__ __launch_bounds__(256) void k_prep(const float* __restrict__ Whh,
                                              const float* __restrict__ Wih,
                                              const float* __restrict__ feat,
                                              bf16* __restrict__ WTs,
                                              bf16* __restrict__ WIE,
                                              bf16* __restrict__ featB,
                                              float* __restrict__ WIT) {
    int t = blockIdx.x * 256 + threadIdx.x;   // 1441 blocks -> 368896 exactly
    if (t < 98304) {
        int T = t >> 10, c = (t >> 6) & 15, l = t & 63;
        int n = T * 16 + (l & 15);
        int k = c * 32 + ((l >> 4) << 3);
        const float* src = Whh + (size_t)n * 512 + k;
        bf16x8 v;
#pragma unroll
        for (int j = 0; j < 8; ++j) v[j] = f2bs(src[j]);
        *(bf16x8*)(WTs + (size_t)t * 8) = v;
    } else if (t < 196608) {
        int u = t - 98304;          // WIT[d][j] = Wih[j][d]
        int d = u / 1536, j = u % 1536;
        WIT[u] = Wih[(size_t)j * 64 + d];
    } else if (t < 208896) {
        int u = t - 196608;         // WIE frags: l, cc, jt, g
        int l = u & 63, cc = (u >> 6) & 1, jg = u >> 7;
        int jt = jg & 31, g = jg >> 5;
        int row = g * 512 + jt * 16 + (l & 15);
        int d0 = cc * 32 + ((l >> 4) << 3);
        const float* src = Wih + (size_t)row * 64 + d0;
        bf16x8 v;
#pragma unroll
        for (int j = 0; j < 8; ++j) v[j] = f2bs(src[j]);
        *(bf16x8*)(WIE + (size_t)u * 8) = v;
    } else {
        int u = t - 208896;         // featB: 160000 threads x 8 elems
        const float* src = feat + (size_t)u * 8;
        bf16x8 v;
#pragma unroll
        for (int j = 0; j < 8; ++j) v[j] = f2bs(src[j]);
        *(bf16x8*)(featB + (size_t)u * 8) = v;
    }
}

// ---- CSR build: count / scan / fill
__global__ __launch_bounds__(256) void k_count(const int* __restrict__ dst,
                                               unsigned* __restrict__ cnt) {
    int e = blockIdx.x * 256 + threadIdx.x;
    if (e < N_EDGES) atomicAdd(&cnt[dst[e]], 1u);
}

#define SCAN_CH 79
__global__ __launch_bounds__(256) void k_scan(const unsigned* __restrict__ cnt,
                                              unsigned* __restrict__ base,
                                              unsigned* __restrict__ cursor) {
    __shared__ unsigned ls[256];
    int t = threadIdx.x;
    int s0 = t * SCAN_CH;
    int s1 = s0 + SCAN_CH < N_NODES ? s0 + SCAN_CH : N_NODES;
    unsigned s = 0;
    for (int i = s0; i < s1; ++i) s += cnt[i];
    ls[t] = s;
    __syncthreads();
    for (int d = 1; d < 256; d <<= 1) {
        unsigned v = (t >= d) ? ls[t - d] : 0u;
        __syncthreads();
        ls[t] += v;
        __syncthreads();
    }
    unsigned run = ls[t] - s;
    for (int i = s0; i < s1; ++i) {
        base[i] = run; cursor[i] = run; run += cnt[i];
    }
    if (t == 255) base[N_NODES] = ls[255];
}

__global__ __launch_bounds__(256) void k_fill(const int* __restrict__ dst,
                                              unsigned* __restrict__ cursor,
                                              unsigned* __restrict__ csr) {
    int e = blockIdx.x * 256 + threadIdx.x;
    if (e < N_EDGES) {
        unsigned p = atomicAdd(&cursor[dst[e]], 1u);
        csr[p] = (unsigned)e;
    }
}

// ---- K1: G[n][k][g] = features[n].W_ih + b_ih (interleaved); also H1[n][k] (free)
__global__ __launch_bounds__(256) void k_gi(const float* __restrict__ feat,
                                            const float* __restrict__ WIT,
                                            const float* __restrict__ b_ih,
                                            const float* __restrict__ b_hh,
                                            bf16* __restrict__ G,
                                            bf16* __restrict__ H1) {
    __shared__ float fs[16][64];
    const int n0 = blockIdx.x * 16;
    const int k = blockIdx.y * 256 + threadIdx.x;
    for (int i = threadIdx.x; i < 16 * 64; i += 256)
        fs[0][i] = feat[(size_t)n0 * 64 + i];
    __syncthreads();
    float acc[3][16];
#pragma unroll
    for (int g = 0; g < 3; ++g) {
        float b = b_ih[g * 512 + k];
#pragma unroll
        for (int e = 0; e < 16; ++e) acc[g][e] = b;
    }
    for (int d = 0; d < 64; d += 4) {
        float w[3][4];
#pragma unroll
        for (int u = 0; u < 4; ++u)
#pragma unroll
            for (int g = 0; g < 3; ++g)
                w[g][u] = WIT[(size_t)(d + u) * G3 + g * 512 + k];
#pragma unroll
        for (int e = 0; e < 16; ++e) {
            float4 f = *(const float4*)&fs[e][d];
#pragma unroll
            for (int g = 0; g < 3; ++g)
                acc[g][e] += w[g][0] * f.x + w[g][1] * f.y + w[g][2] * f.z + w[g][3] * f.w;
        }
    }
    const float br = b_hh[k], bz = b_hh[512 + k], bn = b_hh[1024 + k];
#pragma unroll
    for (int e = 0; e < 16; ++e) {
        bf16* dst = G + (size_t)(n0 + e) * G3 + k * 3;
        dst[0] = f2b(acc[0][e]);
        dst[1] = f2b(acc[1][e]);
        dst[2] = f2b(acc[2][e]);
        float r1 = fsig(acc[0][e] + br);
        float z1 = fsig(acc[1][e] + bz);
        float n1 = ftanh(acc[2][e] + r1 * bn);
        H1[(size_t)(n0 + e) * HID + k] = f2b((1.0f - z1) * n1);
    }
}

// ---- K2: GH2[n] = H1[n] @ W_hh^T + b_hh. M=64/block (R1's best-measured
// config: total 765us), per-gate double-buffered staging (2x16 KB LDS).
__global__ __launch_bounds__(256, 4) void k_gh2(const bf16* __restrict__ H1,
                                                const bf16* __restrict__ WTs,
                                                const float* __restrict__ b_hh,
                                                bf16* __restrict__ GH2) {
    __shared__ short Bs[2][8192];   // 32 KB
    const int tid = threadIdx.x;
    const int wave = tid >> 6, lane = tid & 63;
    const int m0 = blockIdx.x * 64;
    const int k0 = (lane >> 4) << 3;

    bf16x8 afrag[16];
    {
        int row = m0 + wave * 16 + (lane & 15);
        int ar = row < N_NODES ? row : N_NODES - 1;
#pragma unroll
        for (int c = 0; c < 16; ++c)
            afrag[c] = *(const bf16x8*)(H1 + (size_t)ar * HID + c * 32 + k0);
    }

    const int col = lane & 15;
    const int qb = (lane >> 4) << 2;
    const int boff = lane * 8;

    // prologue: stage (jt=0, gate=0) into buf 0
#pragma unroll
    for (int i = 0; i < 4; ++i) {
        int q = tid + i * 256;
        g2l16(WTs + (size_t)q * 8, &Bs[0][q * 8]);
    }
    __syncthreads();

    int cur = 0;
    for (int jt = 0; jt < 32; ++jt) {
        const int cj = jt * 16 + col;
        f32x4 a0 = {0, 0, 0, 0}, a1 = {0, 0, 0, 0}, a2 = {0, 0, 0, 0};
        const float br = b_hh[cj], bz = b_hh[512 + cj], bn = b_hh[1024 + cj];
        // ---- phase gate 0: stage gate1, compute gate0
        {
#pragma unroll
            for (int i = 0; i < 4; ++i) {
                int q = tid + i * 256;
                g2l16(WTs + 262144 + (size_t)jt * 8192 + q * 8, &Bs[cur ^ 1][q * 8]);
            }
            const short* cb = &Bs[cur][0];
#pragma unroll
            for (int c = 0; c < 16; ++c) {
                bf16x8 b = *(const bf16x8*)&cb[c * 512 + boff];
                a0 = __builtin_amdgcn_mfma_f32_16x16x32_bf16(afrag[c], b, a0, 0, 0, 0);
            }
            __syncthreads();
            cur ^= 1;
        }
        // ---- phase gate 1: stage gate2, compute gate1
        {
#pragma unroll
            for (int i = 0; i < 4; ++i) {
                int q = tid + i * 256;
                g2l16(WTs + 524288 + (size_t)jt * 8192 + q * 8, &Bs[cur ^ 1][q * 8]);
            }
            const short* cb = &Bs[cur][0];
#pragma unroll
            for (int c = 0; c < 16; ++c) {
                bf16x8 b = *(const bf16x8*)&cb[c * 512 + boff];
                a1 = __builtin_amdgcn_mfma_f32_16x16x32_bf16(afrag[c], b, a1, 0, 0, 0);
            }
            __syncthreads();
            cur ^= 1;
        }
        // ---- phase gate 2: stage next jt gate0, compute gate2, epilogue
        {
            if (jt < 31) {
#pragma unroll
                for (int i = 0; i < 4; ++i) {
                    int q = tid + i * 256;
                    g2l16(WTs + (size_t)(jt + 1) * 8192 + q * 8, &Bs[cur ^ 1][q * 8]);
                }
            }
            const short* cb = &Bs[cur][0];
#pragma unroll
            for (int c = 0; c < 16; ++c) {
                bf16x8 b = *(const bf16x8*)&cb[c * 512 + boff];
                a2 = __builtin_amdgcn_mfma_f32_16x16x32_bf16(afrag[c], b, a2, 0, 0, 0);
            }
#pragma unroll
            for (int q = 0; q < 4; ++q) {
                int e = m0 + wave * 16 + qb + q;
                if (e < N_NODES) {
                    bf16* dst = GH2 + (size_t)e * G3 + cj * 3;
                    dst[0] = f2b(a0[q] + br);
                    dst[1] = f2b(a1[q] + bz);
                    dst[2] = f2b(a2[q] + bn);
                }
            }
            __syncthreads();
            cur ^= 1;
        }
    }
}

// ---- K3: per-edge h2 = GRUstep2(G[i1], GH2[i0], H1[i0]) elementwise
__global__ __launch_bounds__(256) void k_h2(const bf16* __restrict__ G,
                                            const bf16* __restrict__ GH2,
                                            const bf16* __restrict__ H1,
                                            const int* __restrict__ emi,
                                            bf16* __restrict__ h2) {
    size_t i = (size_t)blockIdx.x * 256 + threadIdx.x;   // 25000 blocks exactly
    int e = (int)(i >> 6);
    int kc = (int)(i & 63) * 8;
    int i0 = emi[(size_t)e * 3 + 0];
    int i1 = emi[(size_t)e * 3 + 1];
    const bf16* g1p = G + (size_t)i1 * G3 + kc * 3;
    const bf16* ghp = GH2 + (size_t)i0 * G3 + kc * 3;
    bf16x8 h1v = *(const bf16x8*)(H1 + (size_t)i0 * HID + kc);
    short s1[24], sh[24];
    {
        bf16x8 a0 = *(const bf16x8*)g1p, a1 = *(const bf16x8*)(g1p + 8), a2 = *(const bf16x8*)(g1p + 16);
        bf16x8 c0 = *(const bf16x8*)ghp, c1 = *(const bf16x8*)(ghp + 8), c2 = *(const bf16x8*)(ghp + 16);
#pragma unroll
        for (int j = 0; j < 8; ++j) {
            s1[j] = a0[j]; s1[8 + j] = a1[j]; s1[16 + j] = a2[j];
            sh[j] = c0[j]; sh[8 + j] = c1[j]; sh[16 + j] = c2[j];
        }
    }
    bf16x8 out;
#pragma unroll
    for (int j = 0; j < 8; ++j) {
        float r = fsig(bs2f(s1[j * 3 + 0]) + bs2f(sh[j * 3 + 0]));
        float z = fsig(bs2f(s1[j * 3 + 1]) + bs2f(sh[j * 3 + 1]));
        float n = ftanh(bs2f(s1[j * 3 + 2]) + r * bs2f(sh[j * 3 + 2]));
        out[j] = f2bs((1.0f - z) * n + z * bs2f(h1v[j]));
    }
    *(bf16x8*)(h2 + (size_t)e * HID + kc) = out;
}

// ---- K4: fused h3 = GRUstep3 (K-extended GEMM, R4's verified 293us
// structure) + FUSED ATTENTION LOGITS. The block produces the complete h3
// rows for its 64 edges across the jt loop; head h = jt>>2 completes every
// 4 jt. Per-lane hacc[4] accumulates hv*attn[cj] (attn in LDS); at each
// head boundary a 16-lane butterfly reduces cols, lane0 of each group does
// the leaky-relu + a[] store + amax atomicMax. This deletes k_logits
// (102 MB re-read + its launch) for ~free, riding the kernel's proven slack.
__global__ __launch_bounds__(256, 3) void k_gemm3(const bf16* __restrict__ featB,
                                                  const bf16* __restrict__ WTs,
                                                  const bf16* __restrict__ WIE,
                                                  const float* __restrict__ b_ih,
                                                  const float* __restrict__ b_hh,
                                                  const int* __restrict__ emi,
                                                  const int* __restrict__ dst,
                                                  const float* __restrict__ attn,
                                                  bf16* __restrict__ h2,
                                                  float* __restrict__ a,
                                                  unsigned* __restrict__ amax) {
    __shared__ short Bs[2][9216];   // 36 KB: per buf 16KB Whh + 2KB WIE
    __shared__ int si2[64];
    __shared__ int sdst[64];
    __shared__ float As[512];       // attn table (8 heads x 64)
    const int tid = threadIdx.x;
    const int wave = tid >> 6, lane = tid & 63;
    const int m0 = blockIdx.x * 64;
    if (tid < 64) {
        int e = m0 + tid;
        int ec = e < N_EDGES ? e : N_EDGES - 1;
        si2[tid] = emi[(size_t)ec * 3 + 2];
        sdst[tid] = dst[ec];
    }
    As[tid] = attn[tid];
    As[256 + tid] = attn[256 + tid];
    const int k0 = (lane >> 4) << 3;
    const int col = lane & 15;
    const int qb = (lane >> 4) << 2;
    const int boff = lane * 8;

    // prologue: stage (jt=0, gate r) into buf 0
#pragma unroll
    for (int i = 0; i < 4; ++i) {
        int q = tid + i * 256;
        g2l16(WTs + (size_t)q * 8, &Bs[0][q * 8]);
    }
    if (tid < 128) g2l16(WIE + (size_t)tid * 8, &Bs[0][8192 + tid * 8]);
    __syncthreads();   // buf0 staged + si2/sdst/As visible

    // A frags: 16 chunks of own h2 row + 2 chunks of gathered featB[i2]
    bf16x8 afrag[18];
    {
        int row = m0 + wave * 16 + (lane & 15);
        int ar = row < N_EDGES ? row : N_EDGES - 1;
#pragma unroll
        for (int c = 0; c < 16; ++c)
            afrag[c] = *(const bf16x8*)(h2 + (size_t)ar * HID + c * 32 + k0);
        int i2r = si2[wave * 16 + (lane & 15)];
        afrag[16] = *(const bf16x8*)(featB + (size_t)i2r * 64 + k0);
        afrag[17] = *(const bf16x8*)(featB + (size_t)i2r * 64 + 32 + k0);
    }

    float hacc[4] = {0.f, 0.f, 0.f, 0.f};
    int cur = 0;
    for (int jt = 0; jt < 32; ++jt) {
        const int cj = jt * 16 + col;
        f32x4 ar_ = {0, 0, 0, 0}, az_ = {0, 0, 0, 0};
        f32x4 ahn = {0, 0, 0, 0}, ain = {0, 0, 0, 0};
        float bihr, bihz, bihn, bhhr, bhhz, bhhn;
        unsigned short ph[4];
        // ---- phase r: prefetch ph + biases, stage z-tile, compute r (18 chunks)
        {
            bihr = b_ih[cj]; bihz = b_ih[512 + cj]; bihn = b_ih[1024 + cj];
            bhhr = b_hh[cj]; bhhz = b_hh[512 + cj]; bhhn = b_hh[1024 + cj];
#pragma unroll
            for (int q = 0; q < 4; ++q) {
                int e = m0 + wave * 16 + qb + q;
                int ec = e < N_EDGES ? e : N_EDGES - 1;
                ph[q] = ((const unsigned short*)h2)[(size_t)ec * HID + cj];
            }
#pragma unroll
            for (int i = 0; i < 4; ++i) {
                int q = tid + i * 256;
                g2l16(WTs + 262144 + (size_t)jt * 8192 + q * 8, &Bs[cur ^ 1][q * 8]);
            }
            if (tid < 128)
                g2l16(WIE + 32768 + (size_t)jt * 1024 + tid * 8, &Bs[cur ^ 1][8192 + tid * 8]);
            const short* cb = &Bs[cur][0];
#pragma unroll
            for (int c = 0; c < 16; ++c) {
                bf16x8 b = *(const bf16x8*)&cb[c * 512 + boff];
                ar_ = __builtin_amdgcn_mfma_f32_16x16x32_bf16(afrag[c], b, ar_, 0, 0, 0);
            }
            {
                bf16x8 b16 = *(const bf16x8*)&cb[8192 + boff];
                bf16x8 b17 = *(const bf16x8*)&cb[8192 + 512 + boff];
                ar_ = __builtin_amdgcn_mfma_f32_16x16x32_bf16(afrag[16], b16, ar_, 0, 0, 0);
                ar_ = __builtin_amdgcn_mfma_f32_16x16x32_bf16(afrag[17], b17, ar_, 0, 0, 0);
            }
            __syncthreads();
            cur ^= 1;
        }
        // ---- phase z: stage n-tile, compute z (18 chunks)
        {
#pragma unroll
            for (int i = 0; i < 4; ++i) {
                int q = tid + i * 256;
                g2l16(WTs + 524288 + (size_t)jt * 8192 + q * 8, &Bs[cur ^ 1][q * 8]);
            }
            if (tid < 128)
                g2l16(WIE + 65536 + (size_t)jt * 1024 + tid * 8, &Bs[cur ^ 1][8192 + tid * 8]);
            const short* cb = &Bs[cur][0];
#pragma unroll
            for (int c = 0; c < 16; ++c) {
                bf16x8 b = *(const bf16x8*)&cb[c * 512 + boff];
                az_ = __builtin_amdgcn_mfma_f32_16x16x32_bf16(afrag[c], b, az_, 0, 0, 0);
            }
            {
                bf16x8 b16 = *(const bf16x8*)&cb[8192 + boff];
                bf16x8 b17 = *(const bf16x8*)&cb[8192 + 512 + boff];
                az_ = __builtin_amdgcn_mfma_f32_16x16x32_bf16(afrag[16], b16, az_, 0, 0, 0);
                az_ = __builtin_amdgcn_mfma_f32_16x16x32_bf16(afrag[17], b17, az_, 0, 0, 0);
            }
            __syncthreads();
            cur ^= 1;
        }
        // ---- phase n: stage next-jt r-tile, compute hn (16) + in (2),
        //      fused GRU epilogue + logit accumulation
        {
            if (jt < 31) {
#pragma unroll
                for (int i = 0; i < 4; ++i) {
                    int q = tid + i * 256;
                    g2l16(WTs + (size_t)(jt + 1) * 8192 + q * 8, &Bs[cur ^ 1][q * 8]);
                }
                if (tid < 128)
                    g2l16(WIE + (size_t)(jt + 1) * 1024 + tid * 8, &Bs[cur ^ 1][8192 + tid * 8]);
            }
            const short* cb = &Bs[cur][0];
#pragma unroll
            for (int c = 0; c < 16; ++c) {
                bf16x8 b = *(const bf16x8*)&cb[c * 512 + boff];
                ahn = __builtin_amdgcn_mfma_f32_16x16x32_bf16(afrag[c], b, ahn, 0, 0, 0);
            }
            {
                bf16x8 b16 = *(const bf16x8*)&cb[8192 + boff];
                bf16x8 b17 = *(const bf16x8*)&cb[8192 + 512 + boff];
                ain = __builtin_amdgcn_mfma_f32_16x16x32_bf16(afrag[16], b16, ain, 0, 0, 0);
                ain = __builtin_amdgcn_mfma_f32_16x16x32_bf16(afrag[17], b17, ain, 0, 0, 0);
            }
            // fused GRU epilogue + per-lane logit partials
            const float aw = As[cj];
#pragma unroll
            for (int q = 0; q < 4; ++q) {
                int e = m0 + wave * 16 + qb + q;
                float r = fsig(ar_[q] + bihr + bhhr);
                float z = fsig(az_[q] + bihz + bhhz);
                float n = ftanh(ain[q] + bihn + r * (ahn[q] + bhhn));
                float hv = (1.0f - z) * n + z * us2f(ph[q]);
                hacc[q] += hv * aw;
                if (e < N_EDGES) h2[(size_t)e * HID + cj] = f2b(hv);
            }
            // head boundary: reduce 16 cols -> logit, store + segment max
            if ((jt & 3) == 3) {
                const int hd = jt >> 2;
#pragma unroll
                for (int m = 1; m < 16; m <<= 1) {
#pragma unroll
                    for (int q = 0; q < 4; ++q)
                        hacc[q] += __shfl_xor(hacc[q], m, 64);
                }
                if ((lane & 15) == 0) {
#pragma unroll
                    for (int q = 0; q < 4; ++q) {
                        int li = wave * 16 + qb + q;
                        int e = m0 + li;
                        if (e < N_EDGES) {
                            float s = hacc[q];
                            s = (s >= 0.f) ? s : 0.01f * s;
                            a[(size_t)e * NH + hd] = s;
                            atomicMax(&amax[(size_t)sdst[li] * NH + hd], ford(s));
                        }
                    }
                }
                hacc[0] = hacc[1] = hacc[2] = hacc[3] = 0.f;
            }
            __syncthreads();
            cur ^= 1;
        }
    }
}

// ---- K8: fused edge-softmax + aggregation (k_ea folded in).
// out[n][k] = sum_e eft[e][k]*exp(a[e][h]-amax[n][h]) / sum_e exp(...)
// Each thread accumulates acc and dsum in the same CSR loop (dsum identical
// across the 64 threads of a head group — no cross-lane needed); h3 rows
// read ONCE (512-thread blocks) instead of twice.
__global__ __launch_bounds__(512) void k_out(const bf16* __restrict__ eft,
                                             const float* __restrict__ a,
                                             const unsigned* __restrict__ amax,
                                             const unsigned* __restrict__ base,
                                             const unsigned* __restrict__ csr,
                                             float* __restrict__ out) {
    int n = blockIdx.x;
    int k = threadIdx.x;
    int h = k >> 6;
    unsigned b0 = base[n], b1 = base[n + 1];
    float m = iford(amax[(size_t)n * NH + h]);
    float acc = 0.f, dsum = 0.f;
    for (unsigned i = b0; i < b1; ++i) {
        unsigned e = csr[i];
        float ea = __expf(a[(size_t)e * NH + h] - m);
        dsum += ea;
        acc += b2f(eft[(size_t)e * HID + k]) * ea;
    }
    out[(size_t)n * HID + k] = (b1 > b0) ? acc * frcp(dsum) : 0.f;
}

extern "C" void kernel_launch(void* const* d_in, const int* in_sizes, int n_in,
                              void* d_out, int out_size, void* d_ws, size_t ws_size,
                              hipStream_t stream) {
    (void)in_sizes; (void)n_in; (void)ws_size; (void)out_size;
    const float* feat = (const float*)d_in[0];
    const float* W_ih = (const float*)d_in[1];
    const float* W_hh = (const float*)d_in[2];
    const float* b_ih = (const float*)d_in[3];
    const float* b_hh = (const float*)d_in[4];
    const float* attn = (const float*)d_in[5];
    const int* emi = (const int*)d_in[6];
    const int* dst = (const int*)d_in[7];
    float* out = (float*)d_out;

    // workspace layout (bytes) — total ~252.8 MB (proven-safe)
    char* ws = (char*)d_ws;
    bf16* G = (bf16*)ws;                               // 61,440,000 B (interleaved)
    bf16* GH2 = (bf16*)(ws + 61440000);                // 61,440,000 B (interleaved)
    bf16* h2 = (bf16*)(ws + 122880000);                // 102,400,000 B (row-major; h3 in-place)
    bf16* WTs = (bf16*)(ws + 225280000);               // 1,572,864 B
    float* WIT = (float*)(ws + 226852864);             // 393,216 B
    unsigned* amax = (unsigned*)(ws + 230446080);      // 640,000 B
    unsigned* cnt = (unsigned*)(ws + 231726080);       // 80,000 B
    unsigned* base = (unsigned*)(ws + 231806080);      // 80,008 B (20001 u32, pad)
    unsigned* cursor = (unsigned*)(ws + 231886088);    // 80,000 B
    unsigned* csr = (unsigned*)(ws + 231966088);       // 400,000 B
    bf16* H1 = (bf16*)(ws + 232366088);                // 20,480,000 B -> end 252,846,088
    // WIE + featB alias the old `a` slot (written k_prep, read k_gemm3).
    bf16* WIE = (bf16*)(ws + 227246080);               // 196,608 B
    bf16* featB = (bf16*)(ws + 227442688);             // 2,560,000 B -> 230,002,688 (< amax)
    // `a` (3.2 MB) now ALIASES the G region: G is dead after k_h2; k_gemm3
    // (strictly after, same stream) writes a, k_out reads it.
    float* a = (float*)ws;

    // zero amax + (dead denom slot) + cnt (contiguous, keeps proven range)
    (void)hipMemsetAsync(amax, 0, 1360000, stream);

    k_prep<<<1441, 256, 0, stream>>>(W_hh, W_ih, feat, WTs, WIE, featB, WIT);
    k_count<<<391, 256, 0, stream>>>(dst, cnt);
    k_scan<<<1, 256, 0, stream>>>(cnt, base, cursor);
    k_fill<<<391, 256, 0, stream>>>(dst, cursor, csr);
    k_gi<<<dim3(1250, 2), 256, 0, stream>>>(feat, WIT, b_ih, b_hh, G, H1);
    k_gh2<<<313, 256, 0, stream>>>(H1, WTs, b_hh, GH2);
    k_h2<<<25000, 256, 0, stream>>>(G, GH2, H1, emi, h2);
    k_gemm3<<<1563, 256, 0, stream>>>(featB, WTs, WIE, b_ih, b_hh, emi, dst, attn,
                                      h2, a, amax);
    k_out<<<N_NODES, 512, 0, stream>>>(h2, a, amax, base, csr, out);
}

// Round 10
// 772.127 us; speedup vs baseline: 1.4961x; 1.0277x over previous
//
#include <hip/hip_runtime.h>
#include <hip/hip_bf16.h>

#define N_NODES 20000
#define N_EDGES 100000
#define HID 512
#define G3 1536   // 3*HID
#define NH 8
#define OD 64

typedef __hip_bfloat16 bf16;
typedef __attribute__((ext_vector_type(8))) short bf16x8;   // 8 bf16 = 4 VGPRs
typedef __attribute__((ext_vector_type(4))) float f32x4;

__device__ __forceinline__ float frcp(float x) { return __builtin_amdgcn_rcpf(x); }
__device__ __forceinline__ float fsig(float x) { return frcp(1.0f + __expf(-x)); }
// saturation-safe fast tanh (rcp-based)
__device__ __forceinline__ float ftanh(float x) { return 1.0f - 2.0f * frcp(__expf(2.0f * x) + 1.0f); }
__device__ __forceinline__ float b2f(bf16 b) { return __bfloat162float(b); }
__device__ __forceinline__ bf16 f2b(float f) { return __float2bfloat16(f); }
__device__ __forceinline__ float bs2f(short s) {
    return __uint_as_float(((unsigned)(unsigned short)s) << 16);
}
__device__ __forceinline__ float us2f(unsigned short s) {
    return __uint_as_float(((unsigned)s) << 16);
}
__device__ __forceinline__ short f2bs(float f) {
    bf16 b = __float2bfloat16(f);
    return *reinterpret_cast<short*>(&b);
}
__device__ __forceinline__ unsigned ford(float f) {
    unsigned u = __float_as_uint(f);
    return (u & 0x80000000u) ? ~u : (u | 0x80000000u);
}
__device__ __forceinline__ float iford(unsigned u) {
    return __uint_as_float((u & 0x80000000u) ? (u & 0x7fffffffu) : ~u);
}

// async global->LDS 16B; falls back to manual copy if builtin missing
__device__ __forceinline__ void g2l16(const void* g, void* l) {
#if __has_builtin(__builtin_amdgcn_global_load_lds)
    __builtin_amdgcn_global_load_lds((const __attribute__((address_space(1))) char*)g,
                                     (__attribute__((address_space(3))) char*)l, 16, 0, 0);
#else
    *(bf16x8*)l = *(const bf16x8*)g;
#endif
}

// G / GH2 layout: gate-interleaved  X[n*1536 + k*3 + g]; H1/h2: row-major [n][512]

// ---- K0: prep weights.
// WTs : 16x16x32 B-frags of W_hh, [g][jt][8192 shorts]
// WIE : 16x16x32 B-frags of W_ih (K-extension chunks 16-17), [g][jt][2][512 shorts]
// featB: bf16 copy of features [20000][64]
__global__ __launch_bounds__(256) void k_prep(const float* __restrict__ Whh,
                                              const float* __restrict__ Wih,
                                              const float* __restrict__ feat,
                                              bf16* __restrict__ WTs,
                                              bf16* __restrict__ WIE,
                                              bf16* __restrict__ featB,
                                              float* __restrict__ WIT) {
    int t = blockIdx.x * 256 + threadIdx.x;   // 1441 blocks -> 368896 exactly
    if (t < 98304) {
        int T = t >> 10, c = (t >> 6) & 15, l = t & 63;
        int n = T * 16 + (l & 15);
        int k = c * 32 + ((l >> 4) << 3);
        const float* src = Whh + (size_t)n * 512 + k;
        bf16x8 v;
#pragma unroll
        for (int j = 0; j < 8; ++j) v[j] = f2bs(src[j]);
        *(bf16x8*)(WTs + (size_t)t * 8) = v;
    } else if (t < 196608) {
        int u = t - 98304;          // WIT[d][j] = Wih[j][d]
        int d = u / 1536, j = u % 1536;
        WIT[u] = Wih[(size_t)j * 64 + d];
    } else if (t < 208896) {
        int u = t - 196608;         // WIE frags: l, cc, jt, g
        int l = u & 63, cc = (u >> 6) & 1, jg = u >> 7;
        int jt = jg & 31, g = jg >> 5;
        int row = g * 512 + jt * 16 + (l & 15);
        int d0 = cc * 32 + ((l >> 4) << 3);
        const float* src = Wih + (size_t)row * 64 + d0;
        bf16x8 v;
#pragma unroll
        for (int j = 0; j < 8; ++j) v[j] = f2bs(src[j]);
        *(bf16x8*)(WIE + (size_t)u * 8) = v;
    } else {
        int u = t - 208896;         // featB: 160000 threads x 8 elems
        const float* src = feat + (size_t)u * 8;
        bf16x8 v;
#pragma unroll
        for (int j = 0; j < 8; ++j) v[j] = f2bs(src[j]);
        *(bf16x8*)(featB + (size_t)u * 8) = v;
    }
}

// ---- CSR build: count / scan / fill
__global__ __launch_bounds__(256) void k_count(const int* __restrict__ dst,
                                               unsigned* __restrict__ cnt) {
    int e = blockIdx.x * 256 + threadIdx.x;
    if (e < N_EDGES) atomicAdd(&cnt[dst[e]], 1u);
}

#define SCAN_CH 79
__global__ __launch_bounds__(256) void k_scan(const unsigned* __restrict__ cnt,
                                              unsigned* __restrict__ base,
                                              unsigned* __restrict__ cursor) {
    __shared__ unsigned ls[256];
    int t = threadIdx.x;
    int s0 = t * SCAN_CH;
    int s1 = s0 + SCAN_CH < N_NODES ? s0 + SCAN_CH : N_NODES;
    unsigned s = 0;
    for (int i = s0; i < s1; ++i) s += cnt[i];
    ls[t] = s;
    __syncthreads();
    for (int d = 1; d < 256; d <<= 1) {
        unsigned v = (t >= d) ? ls[t - d] : 0u;
        __syncthreads();
        ls[t] += v;
        __syncthreads();
    }
    unsigned run = ls[t] - s;
    for (int i = s0; i < s1; ++i) {
        base[i] = run; cursor[i] = run; run += cnt[i];
    }
    if (t == 255) base[N_NODES] = ls[255];
}

__global__ __launch_bounds__(256) void k_fill(const int* __restrict__ dst,
                                              unsigned* __restrict__ cursor,
                                              unsigned* __restrict__ csr) {
    int e = blockIdx.x * 256 + threadIdx.x;
    if (e < N_EDGES) {
        unsigned p = atomicAdd(&cursor[dst[e]], 1u);
        csr[p] = (unsigned)e;
    }
}

// ---- K1: G[n][k][g] = features[n].W_ih + b_ih (interleaved); also H1[n][k] (free)
__global__ __launch_bounds__(256) void k_gi(const float* __restrict__ feat,
                                            const float* __restrict__ WIT,
                                            const float* __restrict__ b_ih,
                                            const float* __restrict__ b_hh,
                                            bf16* __restrict__ G,
                                            bf16* __restrict__ H1) {
    __shared__ float fs[16][64];
    const int n0 = blockIdx.x * 16;
    const int k = blockIdx.y * 256 + threadIdx.x;
    for (int i = threadIdx.x; i < 16 * 64; i += 256)
        fs[0][i] = feat[(size_t)n0 * 64 + i];
    __syncthreads();
    float acc[3][16];
#pragma unroll
    for (int g = 0; g < 3; ++g) {
        float b = b_ih[g * 512 + k];
#pragma unroll
        for (int e = 0; e < 16; ++e) acc[g][e] = b;
    }
    for (int d = 0; d < 64; d += 4) {
        float w[3][4];
#pragma unroll
        for (int u = 0; u < 4; ++u)
#pragma unroll
            for (int g = 0; g < 3; ++g)
                w[g][u] = WIT[(size_t)(d + u) * G3 + g * 512 + k];
#pragma unroll
        for (int e = 0; e < 16; ++e) {
            float4 f = *(const float4*)&fs[e][d];
#pragma unroll
            for (int g = 0; g < 3; ++g)
                acc[g][e] += w[g][0] * f.x + w[g][1] * f.y + w[g][2] * f.z + w[g][3] * f.w;
        }
    }
    const float br = b_hh[k], bz = b_hh[512 + k], bn = b_hh[1024 + k];
#pragma unroll
    for (int e = 0; e < 16; ++e) {
        bf16* dst = G + (size_t)(n0 + e) * G3 + k * 3;
        dst[0] = f2b(acc[0][e]);
        dst[1] = f2b(acc[1][e]);
        dst[2] = f2b(acc[2][e]);
        float r1 = fsig(acc[0][e] + br);
        float z1 = fsig(acc[1][e] + bz);
        float n1 = ftanh(acc[2][e] + r1 * bn);
        H1[(size_t)(n0 + e) * HID + k] = f2b((1.0f - z1) * n1);
    }
}

// ---- K2: GH2[n] = H1[n] @ W_hh^T + b_hh. M=64/block (best-measured: R1's
// 765us total vs 789-801 for M=128 variants), per-gate double-buffered
// staging (2x16 KB LDS, 4 blocks/CU).
__global__ __launch_bounds__(256, 4) void k_gh2(const bf16* __restrict__ H1,
                                                const bf16* __restrict__ WTs,
                                                const float* __restrict__ b_hh,
                                                bf16* __restrict__ GH2) {
    __shared__ short Bs[2][8192];   // 32 KB
    const int tid = threadIdx.x;
    const int wave = tid >> 6, lane = tid & 63;
    const int m0 = blockIdx.x * 64;
    const int k0 = (lane >> 4) << 3;

    bf16x8 afrag[16];
    {
        int row = m0 + wave * 16 + (lane & 15);
        int ar = row < N_NODES ? row : N_NODES - 1;
#pragma unroll
        for (int c = 0; c < 16; ++c)
            afrag[c] = *(const bf16x8*)(H1 + (size_t)ar * HID + c * 32 + k0);
    }

    const int col = lane & 15;
    const int qb = (lane >> 4) << 2;
    const int boff = lane * 8;

    // prologue: stage (jt=0, gate=0) into buf 0
#pragma unroll
    for (int i = 0; i < 4; ++i) {
        int q = tid + i * 256;
        g2l16(WTs + (size_t)q * 8, &Bs[0][q * 8]);
    }
    __syncthreads();

    int cur = 0;
    for (int jt = 0; jt < 32; ++jt) {
        const int cj = jt * 16 + col;
        f32x4 a0 = {0, 0, 0, 0}, a1 = {0, 0, 0, 0}, a2 = {0, 0, 0, 0};
        const float br = b_hh[cj], bz = b_hh[512 + cj], bn = b_hh[1024 + cj];
        // ---- phase gate 0: stage gate1, compute gate0
        {
#pragma unroll
            for (int i = 0; i < 4; ++i) {
                int q = tid + i * 256;
                g2l16(WTs + 262144 + (size_t)jt * 8192 + q * 8, &Bs[cur ^ 1][q * 8]);
            }
            const short* cb = &Bs[cur][0];
#pragma unroll
            for (int c = 0; c < 16; ++c) {
                bf16x8 b = *(const bf16x8*)&cb[c * 512 + boff];
                a0 = __builtin_amdgcn_mfma_f32_16x16x32_bf16(afrag[c], b, a0, 0, 0, 0);
            }
            __syncthreads();
            cur ^= 1;
        }
        // ---- phase gate 1: stage gate2, compute gate1
        {
#pragma unroll
            for (int i = 0; i < 4; ++i) {
                int q = tid + i * 256;
                g2l16(WTs + 524288 + (size_t)jt * 8192 + q * 8, &Bs[cur ^ 1][q * 8]);
            }
            const short* cb = &Bs[cur][0];
#pragma unroll
            for (int c = 0; c < 16; ++c) {
                bf16x8 b = *(const bf16x8*)&cb[c * 512 + boff];
                a1 = __builtin_amdgcn_mfma_f32_16x16x32_bf16(afrag[c], b, a1, 0, 0, 0);
            }
            __syncthreads();
            cur ^= 1;
        }
        // ---- phase gate 2: stage next jt gate0, compute gate2, epilogue
        {
            if (jt < 31) {
#pragma unroll
                for (int i = 0; i < 4; ++i) {
                    int q = tid + i * 256;
                    g2l16(WTs + (size_t)(jt + 1) * 8192 + q * 8, &Bs[cur ^ 1][q * 8]);
                }
            }
            const short* cb = &Bs[cur][0];
#pragma unroll
            for (int c = 0; c < 16; ++c) {
                bf16x8 b = *(const bf16x8*)&cb[c * 512 + boff];
                a2 = __builtin_amdgcn_mfma_f32_16x16x32_bf16(afrag[c], b, a2, 0, 0, 0);
            }
#pragma unroll
            for (int q = 0; q < 4; ++q) {
                int e = m0 + wave * 16 + qb + q;
                if (e < N_NODES) {
                    bf16* dst = GH2 + (size_t)e * G3 + cj * 3;
                    dst[0] = f2b(a0[q] + br);
                    dst[1] = f2b(a1[q] + bz);
                    dst[2] = f2b(a2[q] + bn);
                }
            }
            __syncthreads();
            cur ^= 1;
        }
    }
}

// ---- K3: per-edge h2 = GRUstep2(G[i1], GH2[i0], H1[i0]) elementwise
__global__ __launch_bounds__(256) void k_h2(const bf16* __restrict__ G,
                                            const bf16* __restrict__ GH2,
                                            const bf16* __restrict__ H1,
                                            const int* __restrict__ emi,
                                            bf16* __restrict__ h2) {
    size_t i = (size_t)blockIdx.x * 256 + threadIdx.x;   // 25000 blocks exactly
    int e = (int)(i >> 6);
    int kc = (int)(i & 63) * 8;
    int i0 = emi[(size_t)e * 3 + 0];
    int i1 = emi[(size_t)e * 3 + 1];
    const bf16* g1p = G + (size_t)i1 * G3 + kc * 3;
    const bf16* ghp = GH2 + (size_t)i0 * G3 + kc * 3;
    bf16x8 h1v = *(const bf16x8*)(H1 + (size_t)i0 * HID + kc);
    short s1[24], sh[24];
    {
        bf16x8 a0 = *(const bf16x8*)g1p, a1 = *(const bf16x8*)(g1p + 8), a2 = *(const bf16x8*)(g1p + 16);
        bf16x8 c0 = *(const bf16x8*)ghp, c1 = *(const bf16x8*)(ghp + 8), c2 = *(const bf16x8*)(ghp + 16);
#pragma unroll
        for (int j = 0; j < 8; ++j) {
            s1[j] = a0[j]; s1[8 + j] = a1[j]; s1[16 + j] = a2[j];
            sh[j] = c0[j]; sh[8 + j] = c1[j]; sh[16 + j] = c2[j];
        }
    }
    bf16x8 out;
#pragma unroll
    for (int j = 0; j < 8; ++j) {
        float r = fsig(bs2f(s1[j * 3 + 0]) + bs2f(sh[j * 3 + 0]));
        float z = fsig(bs2f(s1[j * 3 + 1]) + bs2f(sh[j * 3 + 1]));
        float n = ftanh(bs2f(s1[j * 3 + 2]) + r * bs2f(sh[j * 3 + 2]));
        out[j] = f2bs((1.0f - z) * n + z * bs2f(h1v[j]));
    }
    *(bf16x8*)(h2 + (size_t)e * HID + kc) = out;
}

// ---- K4: fused h3 = GRUstep3 with K-extended GEMM (no G gather) — R4's
// verified 293us floor structure, UNMODIFIED (R8's logits fusion cost +75us
// and was reverted; six structural attacks R0-R7 all landed >= 291us).
__global__ __launch_bounds__(256, 3) void k_gemm3(const bf16* __restrict__ featB,
                                                  const bf16* __restrict__ WTs,
                                                  const bf16* __restrict__ WIE,
                                                  const float* __restrict__ b_ih,
                                                  const float* __restrict__ b_hh,
                                                  const int* __restrict__ emi,
                                                  bf16* __restrict__ h2) {
    __shared__ short Bs[2][9216];   // 36 KB: per buf 16KB W_hh chunks + 2KB W_ih ext
    __shared__ int si2[64];
    const int tid = threadIdx.x;
    const int wave = tid >> 6, lane = tid & 63;
    const int m0 = blockIdx.x * 64;
    if (tid < 64) {
        int e = m0 + tid;
        si2[tid] = emi[(size_t)(e < N_EDGES ? e : N_EDGES - 1) * 3 + 2];
    }
    const int k0 = (lane >> 4) << 3;
    const int col = lane & 15;
    const int qb = (lane >> 4) << 2;
    const int boff = lane * 8;

    // prologue: stage (jt=0, gate r) into buf 0
#pragma unroll
    for (int i = 0; i < 4; ++i) {
        int q = tid + i * 256;
        g2l16(WTs + (size_t)q * 8, &Bs[0][q * 8]);
    }
    if (tid < 128) g2l16(WIE + (size_t)tid * 8, &Bs[0][8192 + tid * 8]);
    __syncthreads();   // buf0 staged + si2 visible

    // A frags: 16 chunks of own h2 row + 2 chunks of gathered featB[i2]
    bf16x8 afrag[18];
    {
        int row = m0 + wave * 16 + (lane & 15);
        int ar = row < N_EDGES ? row : N_EDGES - 1;
#pragma unroll
        for (int c = 0; c < 16; ++c)
            afrag[c] = *(const bf16x8*)(h2 + (size_t)ar * HID + c * 32 + k0);
        int i2r = si2[wave * 16 + (lane & 15)];
        afrag[16] = *(const bf16x8*)(featB + (size_t)i2r * 64 + k0);
        afrag[17] = *(const bf16x8*)(featB + (size_t)i2r * 64 + 32 + k0);
    }

    int cur = 0;
    for (int jt = 0; jt < 32; ++jt) {
        const int cj = jt * 16 + col;
        f32x4 ar_ = {0, 0, 0, 0}, az_ = {0, 0, 0, 0};
        f32x4 ahn = {0, 0, 0, 0}, ain = {0, 0, 0, 0};
        float bihr, bihz, bihn, bhhr, bhhz, bhhn;
        unsigned short ph[4];
        // ---- phase r: prefetch ph + biases, stage z-tile, compute r (18 chunks)
        {
            bihr = b_ih[cj]; bihz = b_ih[512 + cj]; bihn = b_ih[1024 + cj];
            bhhr = b_hh[cj]; bhhz = b_hh[512 + cj]; bhhn = b_hh[1024 + cj];
#pragma unroll
            for (int q = 0; q < 4; ++q) {
                int e = m0 + wave * 16 + qb + q;
                int ec = e < N_EDGES ? e : N_EDGES - 1;
                ph[q] = ((const unsigned short*)h2)[(size_t)ec * HID + cj];
            }
#pragma unroll
            for (int i = 0; i < 4; ++i) {
                int q = tid + i * 256;
                g2l16(WTs + 262144 + (size_t)jt * 8192 + q * 8, &Bs[cur ^ 1][q * 8]);
            }
            if (tid < 128)
                g2l16(WIE + 32768 + (size_t)jt * 1024 + tid * 8, &Bs[cur ^ 1][8192 + tid * 8]);
            const short* cb = &Bs[cur][0];
#pragma unroll
            for (int c = 0; c < 16; ++c) {
                bf16x8 b = *(const bf16x8*)&cb[c * 512 + boff];
                ar_ = __builtin_amdgcn_mfma_f32_16x16x32_bf16(afrag[c], b, ar_, 0, 0, 0);
            }
            {
                bf16x8 b16 = *(const bf16x8*)&cb[8192 + boff];
                bf16x8 b17 = *(const bf16x8*)&cb[8192 + 512 + boff];
                ar_ = __builtin_amdgcn_mfma_f32_16x16x32_bf16(afrag[16], b16, ar_, 0, 0, 0);
                ar_ = __builtin_amdgcn_mfma_f32_16x16x32_bf16(afrag[17], b17, ar_, 0, 0, 0);
            }
            __syncthreads();
            cur ^= 1;
        }
        // ---- phase z: stage n-tile, compute z (18 chunks)
        {
#pragma unroll
            for (int i = 0; i < 4; ++i) {
                int q = tid + i * 256;
                g2l16(WTs + 524288 + (size_t)jt * 8192 + q * 8, &Bs[cur ^ 1][q * 8]);
            }
            if (tid < 128)
                g2l16(WIE + 65536 + (size_t)jt * 1024 + tid * 8, &Bs[cur ^ 1][8192 + tid * 8]);
            const short* cb = &Bs[cur][0];
#pragma unroll
            for (int c = 0; c < 16; ++c) {
                bf16x8 b = *(const bf16x8*)&cb[c * 512 + boff];
                az_ = __builtin_amdgcn_mfma_f32_16x16x32_bf16(afrag[c], b, az_, 0, 0, 0);
            }
            {
                bf16x8 b16 = *(const bf16x8*)&cb[8192 + boff];
                bf16x8 b17 = *(const bf16x8*)&cb[8192 + 512 + boff];
                az_ = __builtin_amdgcn_mfma_f32_16x16x32_bf16(afrag[16], b16, az_, 0, 0, 0);
                az_ = __builtin_amdgcn_mfma_f32_16x16x32_bf16(afrag[17], b17, az_, 0, 0, 0);
            }
            __syncthreads();
            cur ^= 1;
        }
        // ---- phase n: stage next-jt r-tile, compute hn (16) + in (2), epilogue
        {
            if (jt < 31) {
#pragma unroll
                for (int i = 0; i < 4; ++i) {
                    int q = tid + i * 256;
                    g2l16(WTs + (size_t)(jt + 1) * 8192 + q * 8, &Bs[cur ^ 1][q * 8]);
                }
                if (tid < 128)
                    g2l16(WIE + (size_t)(jt + 1) * 1024 + tid * 8, &Bs[cur ^ 1][8192 + tid * 8]);
            }
            const short* cb = &Bs[cur][0];
#pragma unroll
            for (int c = 0; c < 16; ++c) {
                bf16x8 b = *(const bf16x8*)&cb[c * 512 + boff];
                ahn = __builtin_amdgcn_mfma_f32_16x16x32_bf16(afrag[c], b, ahn, 0, 0, 0);
            }
            {
                bf16x8 b16 = *(const bf16x8*)&cb[8192 + boff];
                bf16x8 b17 = *(const bf16x8*)&cb[8192 + 512 + boff];
                ain = __builtin_amdgcn_mfma_f32_16x16x32_bf16(afrag[16], b16, ain, 0, 0, 0);
                ain = __builtin_amdgcn_mfma_f32_16x16x32_bf16(afrag[17], b17, ain, 0, 0, 0);
            }
            // fused GRU epilogue: no gathered operands, all in registers
#pragma unroll
            for (int q = 0; q < 4; ++q) {
                int e = m0 + wave * 16 + qb + q;
                if (e < N_EDGES) {
                    float r = fsig(ar_[q] + bihr + bhhr);
                    float z = fsig(az_[q] + bihz + bhhz);
                    float n = ftanh(ain[q] + bihn + r * (ahn[q] + bhhn));
                    h2[(size_t)e * HID + cj] = f2b((1.0f - z) * n + z * us2f(ph[q]));
                }
            }
            __syncthreads();
            cur ^= 1;
        }
    }
}

// ---- K6: attention logits + leaky relu + segment max (standalone — fusing
// into k_gemm3 cost +75us there, R8 measurement)
__global__ __launch_bounds__(256) void k_logits(const bf16* __restrict__ eft,
                                                const float* __restrict__ attn,
                                                const int* __restrict__ dst,
                                                float* __restrict__ a,
                                                unsigned* __restrict__ amax) {
    int i = blockIdx.x * 256 + threadIdx.x;  // E*NH exactly
    int e = i >> 3, h = i & 7;
    const __hip_bfloat162* f2 = (const __hip_bfloat162*)(eft + (size_t)e * HID + h * OD);
    const float* at = attn + h * OD;
    float s = 0.f;
#pragma unroll
    for (int d = 0; d < OD / 2; ++d) {
        float2 fv = __bfloat1622float2(f2[d]);
        s += fv.x * at[2 * d] + fv.y * at[2 * d + 1];
    }
    s = (s >= 0.f) ? s : 0.01f * s;
    a[i] = s;
    atomicMax(&amax[(size_t)dst[e] * NH + h], ford(s));
}

// ---- K8: fused edge-softmax + aggregation (k_ea folded in, R8-verified).
// out[n][k] = sum_e eft[e][k]*exp(a[e][h]-amax[n][h]) / sum_e exp(...)
// dsum computed redundantly per thread of a head group (no cross-lane);
// h3 rows read ONCE (512-thread blocks).
__global__ __launch_bounds__(512) void k_out(const bf16* __restrict__ eft,
                                             const float* __restrict__ a,
                                             const unsigned* __restrict__ amax,
                                             const unsigned* __restrict__ base,
                                             const unsigned* __restrict__ csr,
                                             float* __restrict__ out) {
    int n = blockIdx.x;
    int k = threadIdx.x;
    int h = k >> 6;
    unsigned b0 = base[n], b1 = base[n + 1];
    float m = iford(amax[(size_t)n * NH + h]);
    float acc = 0.f, dsum = 0.f;
    for (unsigned i = b0; i < b1; ++i) {
        unsigned e = csr[i];
        float ea = __expf(a[(size_t)e * NH + h] - m);
        dsum += ea;
        acc += b2f(eft[(size_t)e * HID + k]) * ea;
    }
    out[(size_t)n * HID + k] = (b1 > b0) ? acc * frcp(dsum) : 0.f;
}

extern "C" void kernel_launch(void* const* d_in, const int* in_sizes, int n_in,
                              void* d_out, int out_size, void* d_ws, size_t ws_size,
                              hipStream_t stream) {
    (void)in_sizes; (void)n_in; (void)ws_size; (void)out_size;
    const float* feat = (const float*)d_in[0];
    const float* W_ih = (const float*)d_in[1];
    const float* W_hh = (const float*)d_in[2];
    const float* b_ih = (const float*)d_in[3];
    const float* b_hh = (const float*)d_in[4];
    const float* attn = (const float*)d_in[5];
    const int* emi = (const int*)d_in[6];
    const int* dst = (const int*)d_in[7];
    float* out = (float*)d_out;

    // workspace layout (bytes) — total ~252.8 MB (proven-safe)
    char* ws = (char*)d_ws;
    bf16* G = (bf16*)ws;                               // 61,440,000 B (interleaved)
    bf16* GH2 = (bf16*)(ws + 61440000);                // 61,440,000 B (interleaved)
    bf16* h2 = (bf16*)(ws + 122880000);                // 102,400,000 B (row-major; h3 in-place)
    bf16* WTs = (bf16*)(ws + 225280000);               // 1,572,864 B
    float* WIT = (float*)(ws + 226852864);             // 393,216 B
    unsigned* amax = (unsigned*)(ws + 230446080);      // 640,000 B
    unsigned* cnt = (unsigned*)(ws + 231726080);       // 80,000 B
    unsigned* base = (unsigned*)(ws + 231806080);      // 80,008 B (20001 u32, pad)
    unsigned* cursor = (unsigned*)(ws + 231886088);    // 80,000 B
    unsigned* csr = (unsigned*)(ws + 231966088);       // 400,000 B
    bf16* H1 = (bf16*)(ws + 232366088);                // 20,480,000 B -> end 252,846,088
    // WIE + featB alias the old `a` slot (written k_prep, read k_gemm3).
    bf16* WIE = (bf16*)(ws + 227246080);               // 196,608 B
    bf16* featB = (bf16*)(ws + 227442688);             // 2,560,000 B -> 230,002,688 (< amax)
    // `a` (3.2 MB) ALIASES the G region: G is dead after k_h2; k_logits
    // (strictly after, same stream) writes a, k_out reads it.
    float* a = (float*)ws;

    // zero amax + (dead slot) + cnt (contiguous, keeps proven range)
    (void)hipMemsetAsync(amax, 0, 1360000, stream);

    k_prep<<<1441, 256, 0, stream>>>(W_hh, W_ih, feat, WTs, WIE, featB, WIT);
    k_count<<<391, 256, 0, stream>>>(dst, cnt);
    k_scan<<<1, 256, 0, stream>>>(cnt, base, cursor);
    k_fill<<<391, 256, 0, stream>>>(dst, cursor, csr);
    k_gi<<<dim3(1250, 2), 256, 0, stream>>>(feat, WIT, b_ih, b_hh, G, H1);
    k_gh2<<<313, 256, 0, stream>>>(H1, WTs, b_hh, GH2);
    k_h2<<<25000, 256, 0, stream>>>(G, GH2, H1, emi, h2);
    k_gemm3<<<1563, 256, 0, stream>>>(featB, WTs, WIE, b_ih, b_hh, emi, h2);
    k_logits<<<3125, 256, 0, stream>>>(h2, attn, dst, a, amax);
    k_out<<<N_NODES, 512, 0, stream>>>(h2, a, amax, base, csr, out);
}